// Round 2
// baseline (391.372 us; speedup 1.0000x reference)
//
#include <hip/hip_runtime.h>

// ---------------- problem constants ----------------
#define NNODES 200
#define FEATX  2600      // 50*52
#define FEAT   2800      // FEATX + NNODES
#define NCH    44        // 44 * 64 = 2816 padded K
#define N1     128

typedef _Float16 f16;
typedef _Float16 f16x8 __attribute__((ext_vector_type(8)));
typedef float    f32x4 __attribute__((ext_vector_type(4)));

// ---------------- workspace byte offsets ----------------
#define W1T_OFF   0u          // 44 * 16384 = 720896  (swizzled fp16 W1^T chunks)
#define W2T_OFF   720896u     // 32768 (swizzled fp16 W2^T)
#define W3T_OFF   753664u     // 16384 (swizzled fp16 W3^T)
#define WG_OFF    770048u     // 200*128*4 = 102400 (fp32 Wg')
#define B1P_OFF   872448u     // 512   (fp32 folded bias b1')
#define HW_OFF    872960u     // 16    (fp32 hw_val[3])
#define WE_OFF    874816u     // 3200  (fp32 per-edge weight)

__device__ __forceinline__ void gl_lds16(const void* g, void* l) {
  __builtin_amdgcn_global_load_lds(
      (const __attribute__((address_space(1))) unsigned int*)g,
      (__attribute__((address_space(3))) unsigned int*)l, 16, 0, 0);
}

// ============ prep1: degrees->norms, hw_val, edge weights, folded b1' ============
__global__ void prep1(const int* __restrict__ esrc, const int* __restrict__ edst,
                      const float* __restrict__ emb, const float* __restrict__ gcw,
                      const float* __restrict__ gcb, const float* __restrict__ W1,
                      const float* __restrict__ b1, char* __restrict__ ws) {
  __shared__ float dg[2][NNODES];
  const int tid = threadIdx.x;  // 256
  for (int i = tid; i < 2 * NNODES; i += 256) ((float*)dg)[i] = 0.f;
  __syncthreads();
  for (int e = tid; e < 800; e += 256) {
    atomicAdd(&dg[0][esrc[e]], 1.f);
    atomicAdd(&dg[1][edst[e]], 1.f);
  }
  __syncthreads();
  for (int i = tid; i < 2 * NNODES; i += 256) {
    float* p = (float*)dg + i;
    *p = 1.f / sqrtf(fmaxf(*p, 1.f));
  }
  if (tid < 3) {
    float s = 0.f;
    for (int q = 0; q < 5; ++q) s += emb[tid * 5 + q] * gcw[q];
    ((float*)(ws + HW_OFF))[tid] = s;
  }
  __syncthreads();
  float* we = (float*)(ws + WE_OFF);
  for (int e = tid; e < 800; e += 256)
    we[e] = dg[0][esrc[e]] * dg[1][edst[e]];
  if (tid < 128) {
    float s = 0.f;
    for (int d = 0; d < NNODES; ++d) s += W1[(FEATX + d) * N1 + tid];
    ((float*)(ws + B1P_OFF))[tid] = b1[tid] + gcb[0] * s;
  }
}

// ============ prepWg: per-src-node gather (no atomics, no zero-init) ============
// Wg'[n,j] = sum_{e: esrc[e]==n} we[e] * W1[(FEATX+edst[e])*128 + j]
__global__ void prepWg(const int* __restrict__ esrc, const int* __restrict__ edst,
                       const float* __restrict__ W1, char* __restrict__ ws) {
  __shared__ int   se[800];
  __shared__ short sd[800];
  __shared__ float swe[800];
  const int n = blockIdx.x;       // 0..199
  const int j = threadIdx.x;      // 128
  const float* we = (const float*)(ws + WE_OFF);
  for (int e = j; e < 800; e += 128) {
    se[e] = esrc[e]; sd[e] = (short)edst[e]; swe[e] = we[e];
  }
  __syncthreads();
  float acc = 0.f;
  for (int e = 0; e < 800; ++e) {
    if (se[e] == n) acc += swe[e] * W1[(FEATX + (int)sd[e]) * N1 + j];
  }
  ((float*)(ws + WG_OFF))[n * N1 + j] = acc;
}

// ============ pack: coalesced read -> LDS transpose/swizzle -> coalesced write ====
__global__ void pack(const float* __restrict__ W1, const float* __restrict__ W2,
                     const float* __restrict__ W3, char* __restrict__ ws) {
  __shared__ __align__(16) char tile[32768];
  const int bid = blockIdx.x, tid = threadIdx.x;  // 46 x 256
  if (bid < NCH) {
    const float* wg = (const float*)(ws + WG_OFF);
    const int c = tid & 127, kh = tid >> 7;
    for (int kk = kh; kk < 64; kk += 2) {
      const int k = bid * 64 + kk;
      float v;
      if (k < FEATX) v = W1[k * N1 + c];
      else if (k < FEAT) v = wg[(k - FEATX) * N1 + c];
      else v = 0.f;
      *(f16*)(tile + ((c * 128 + kk * 2) ^ ((c & 7) << 4))) = (f16)v;
    }
    __syncthreads();
    char* dst = ws + W1T_OFF + bid * 16384;
    for (int i = 0; i < 4; ++i)
      *(uint4*)(dst + tid * 16 + i * 4096) = *(const uint4*)(tile + tid * 16 + i * 4096);
  } else if (bid == NCH) {
    const int c = tid & 127, kh = tid >> 7;
    for (int k = kh; k < 128; k += 2) {
      const float v = W2[k * 128 + c];
      *(f16*)(tile + ((c * 256 + k * 2) ^ ((c & 7) << 4))) = (f16)v;
    }
    __syncthreads();
    char* dst = ws + W2T_OFF;
    for (int i = 0; i < 8; ++i)
      *(uint4*)(dst + tid * 16 + i * 4096) = *(const uint4*)(tile + tid * 16 + i * 4096);
  } else {
    const int c = tid & 63, kh = tid >> 6;
    for (int k = kh; k < 128; k += 4) {
      const float v = W3[k * 64 + c];
      *(f16*)(tile + ((c * 256 + k * 2) ^ ((c & 7) << 4))) = (f16)v;
    }
    __syncthreads();
    char* dst = ws + W3T_OFF;
    for (int i = 0; i < 4; ++i)
      *(uint4*)(dst + tid * 16 + i * 4096) = *(const uint4*)(tile + tid * 16 + i * 4096);
  }
}

// ============ fused main ============
// A (x/apps) loaded direct-to-register 2 iters ahead; B (W1T chunks) via
// global_load_lds into 3 LDS buffers; one raw s_barrier + counted vmcnt(6)
// per iteration (6 = one iteration's vmem ops: 2 gl_lds + 4 A dwordx4).
__global__ __launch_bounds__(512, 2)
void fused_main(const float* __restrict__ x, const int* __restrict__ apps,
                const char* __restrict__ ws, const float* __restrict__ b2,
                const float* __restrict__ b3, const float* __restrict__ W4,
                const float* __restrict__ b4, float* __restrict__ out) {
  __shared__ __align__(16) char lds[81920];
  char*  sB    = lds;                    // loop: 3 x 16384 | epilogue: W2T(32K)+W3T(16K)
  char*  sAct1 = lds + 49152;            // 16K f16 [64][128] swizzled
  char*  sAct2 = lds + 65536;            // 16K
  float* sAct3 = (float*)(lds + 49152);  // 16K fp32 [64][64] (aliases sAct1)

  const int tid  = threadIdx.x;
  const int lane = tid & 63;
  const int w    = tid >> 6;     // 0..7
  const int lrow = lane & 15;
  const int lk   = lane >> 4;    // 0..3
  const int wr   = w >> 1;       // 0..3  (16-row slice)
  const int wc   = w & 1;        // 0..1  (64-col slice)
  const int blk  = blockIdx.x;

  const float* hwv = (const float*)(ws + HW_OFF);
  const float hw0 = hwv[0], hw1 = hwv[1], hw2 = hwv[2];

  const int row_g = blk * 64 + wr * 16 + lrow;
  const float* xrow = x + (size_t)row_g * FEATX;
  const int*   irow = apps + (size_t)row_g * NNODES;

  int boff[2][4];
#pragma unroll
  for (int ks = 0; ks < 2; ++ks)
#pragma unroll
    for (int f = 0; f < 4; ++f) {
      const int c = wc * 64 + f * 16 + lrow;
      boff[ks][f] = ((c * 128 + ks * 64 + lk * 16) ^ ((lrow & 7) << 4));
    }

  const f32x4 zed = {0.f, 0.f, 0.f, 0.f};
  f32x4 acc1[4] = {zed, zed, zed, zed};

  auto issueB = [&](int tc, int buf) {
    const char* src = ws + W1T_OFF + (size_t)tc * 16384;
    char* dst = sB + buf * 16384;
#pragma unroll
    for (int r = 0; r < 2; ++r) {
      const int o = r * 8192 + w * 1024;
      gl_lds16(src + o + lane * 16, dst + o);
    }
  };
  auto issueA = [&](int tc, uint4 (&ar)[2][2]) {
#pragma unroll
    for (int ks = 0; ks < 2; ++ks) {
      const int k0 = tc * 64 + ks * 32 + lk * 8;
      const char* p;
      if (k0 + 8 <= FEATX)  p = (const char*)(xrow + k0);
      else if (k0 < FEAT)   p = (const char*)(irow + (k0 - FEATX));
      else                  p = (const char*)xrow;   // dummy safe addr, zeroed at cvt
      ar[ks][0] = *(const uint4*)p;
      ar[ks][1] = *(const uint4*)(p + 16);
    }
  };
  auto cvtA = [&](int t, const uint4 (&ar)[2][2], f16x8 (&af)[2]) {
#pragma unroll
    for (int ks = 0; ks < 2; ++ks) {
      const int k0 = t * 64 + ks * 32 + lk * 8;
      union { uint4 u[2]; unsigned ui[8]; float f[8]; } d;
      d.u[0] = ar[ks][0]; d.u[1] = ar[ks][1];
      union { f16x8 v; f16 h[8]; } r;
      if (k0 + 8 <= FEATX) {
#pragma unroll
        for (int j2 = 0; j2 < 8; ++j2) r.h[j2] = (f16)d.f[j2];
      } else if (k0 < FEAT) {
#pragma unroll
        for (int j2 = 0; j2 < 8; ++j2) {
          const unsigned a = d.ui[j2];
          r.h[j2] = (f16)(a == 0u ? hw0 : (a == 1u ? hw1 : hw2));
        }
      } else {
#pragma unroll
        for (int j2 = 0; j2 < 8; ++j2) r.h[j2] = (f16)0.f;
      }
      af[ks] = r.v;
    }
  };
  auto compute = [&](const f16x8 (&af)[2], int buf) {
    const char* b = sB + buf * 16384;
#pragma unroll
    for (int ks = 0; ks < 2; ++ks)
#pragma unroll
      for (int f = 0; f < 4; ++f) {
        const f16x8 bf = *(const f16x8*)(b + boff[ks][f]);
        acc1[f] = __builtin_amdgcn_mfma_f32_16x16x32_f16(af[ks], bf, acc1[f], 0, 0, 0);
      }
  };

  uint4 arA[2][2], arB[2][2];
  f16x8 af[2];

  // prologue: 2 tiles in flight
  issueB(0, 0); issueA(0, arA);
  issueB(1, 1); issueA(1, arB);

  for (int t = 0; t < NCH; t += 2) {
    {
      asm volatile("s_waitcnt vmcnt(6)" ::: "memory");
      __builtin_amdgcn_s_barrier();
      __builtin_amdgcn_sched_barrier(0);
      const int tc = (t + 2 < NCH) ? t + 2 : NCH - 1;
      issueB(tc, (t + 2) % 3);
      cvtA(t, arA, af);
      issueA(tc, arA);
      compute(af, t % 3);
    }
    {
      asm volatile("s_waitcnt vmcnt(6)" ::: "memory");
      __builtin_amdgcn_s_barrier();
      __builtin_amdgcn_sched_barrier(0);
      const int t1 = t + 1;
      const int tc = (t1 + 2 < NCH) ? t1 + 2 : NCH - 1;
      issueB(tc, (t1 + 2) % 3);
      cvtA(t1, arB, af);
      issueA(tc, arB);
      compute(af, t1 % 3);
    }
  }
  __syncthreads();   // drain tail dummy loads; all buf reads complete

  // prefetch W2^T + W3^T (48KB contiguous in ws) into lds[0..49152)
#pragma unroll
  for (int r = 0; r < 6; ++r) {
    const int o = r * 8192 + w * 1024;
    gl_lds16(ws + W2T_OFF + o + lane * 16, lds + o);
  }

  // -------- epilogue 1: + b1', softplus -> sAct1 (f16, 256B rows, swizzled) ----
  const float* b1p = (const float*)(ws + B1P_OFF);
#pragma unroll
  for (int f = 0; f < 4; ++f) {
    const int col = wc * 64 + f * 16 + lrow;
    const float bb = b1p[col];
#pragma unroll
    for (int r = 0; r < 4; ++r) {
      const int row = wr * 16 + lk * 4 + r;
      float v = acc1[f][r] + bb;
      v = fmaxf(v, 0.f) + log1pf(expf(-fabsf(v)));
      *(f16*)(sAct1 + ((row * 256 + col * 2) ^ ((row & 7) << 4))) = (f16)v;
    }
  }
  __syncthreads();   // drains W23 gl_lds + act1 writes

  // -------- GEMM2: a1[64x128] @ W2[128x128], softplus -> sAct2 --------
  f32x4 acc2[4] = {zed, zed, zed, zed};
#pragma unroll
  for (int ks = 0; ks < 4; ++ks) {
    const int ar = wr * 16 + lrow;
    const f16x8 a2 = *(const f16x8*)(sAct1 + ((ar * 256 + ks * 64 + lk * 16) ^ ((lrow & 7) << 4)));
#pragma unroll
    for (int f = 0; f < 4; ++f) {
      const int c = wc * 64 + f * 16 + lrow;
      const f16x8 bf = *(const f16x8*)(lds + ((c * 256 + ks * 64 + lk * 16) ^ ((lrow & 7) << 4)));
      acc2[f] = __builtin_amdgcn_mfma_f32_16x16x32_f16(a2, bf, acc2[f], 0, 0, 0);
    }
  }
#pragma unroll
  for (int f = 0; f < 4; ++f) {
    const int col = wc * 64 + f * 16 + lrow;
    const float bb = b2[col];
#pragma unroll
    for (int r = 0; r < 4; ++r) {
      const int row = wr * 16 + lk * 4 + r;
      float v = acc2[f][r] + bb;
      v = fmaxf(v, 0.f) + log1pf(expf(-fabsf(v)));
      *(f16*)(sAct2 + ((row * 256 + col * 2) ^ ((row & 7) << 4))) = (f16)v;
    }
  }
  __syncthreads();

  // -------- GEMM3: a2[64x128] @ W3[128x64], tanhshrink -> sAct3 (fp32) --------
  f32x4 acc3[2] = {zed, zed};
  const char* w3p = lds + 32768;
#pragma unroll
  for (int ks = 0; ks < 4; ++ks) {
    const int ar = wr * 16 + lrow;
    const f16x8 a3 = *(const f16x8*)(sAct2 + ((ar * 256 + ks * 64 + lk * 16) ^ ((lrow & 7) << 4)));
#pragma unroll
    for (int f = 0; f < 2; ++f) {
      const int c = wc * 32 + f * 16 + lrow;
      const f16x8 bf = *(const f16x8*)(w3p + ((c * 256 + ks * 64 + lk * 16) ^ ((lrow & 7) << 4)));
      acc3[f] = __builtin_amdgcn_mfma_f32_16x16x32_f16(a3, bf, acc3[f], 0, 0, 0);
    }
  }
#pragma unroll
  for (int f = 0; f < 2; ++f) {
    const int col = wc * 32 + f * 16 + lrow;
    const float bb = b3[col];
#pragma unroll
    for (int r = 0; r < 4; ++r) {
      const int row = wr * 16 + lk * 4 + r;
      const float z = acc3[f][r] + bb;
      sAct3[row * 64 + col] = z - tanhf(z);
    }
  }
  __syncthreads();

  // -------- GEMM4 (vector fp32): a3[64x64] @ W4[64x2] + b4, sigmoid --------
  if (tid < 128) {
    const int row = tid >> 1, j = tid & 1;
    float a4 = b4[j];
#pragma unroll 8
    for (int k = 0; k < 64; ++k)
      a4 += sAct3[row * 64 + k] * W4[k * 2 + j];
    out[(size_t)(blk * 64 + row) * 2 + j] = 1.f / (1.f + expf(-a4));
  }
}

// ---------------- launch ----------------
extern "C" void kernel_launch(void* const* d_in, const int* in_sizes, int n_in,
                              void* d_out, int out_size, void* d_ws, size_t ws_size,
                              hipStream_t stream) {
  const float* x    = (const float*)d_in[0];
  const int*   apps = (const int*)d_in[1];
  const int*   esrc = (const int*)d_in[2];
  const int*   edst = (const int*)d_in[3];
  const float* emb  = (const float*)d_in[4];
  const float* gcw  = (const float*)d_in[5];
  const float* gcb  = (const float*)d_in[6];
  const float* W1   = (const float*)d_in[7];
  const float* b1   = (const float*)d_in[8];
  const float* W2   = (const float*)d_in[9];
  const float* b2   = (const float*)d_in[10];
  const float* W3   = (const float*)d_in[11];
  const float* b3   = (const float*)d_in[12];
  const float* W4   = (const float*)d_in[13];
  const float* b4   = (const float*)d_in[14];
  char* ws = (char*)d_ws;
  float* out = (float*)d_out;

  hipLaunchKernelGGL(prep1, dim3(1), dim3(256), 0, stream,
                     esrc, edst, emb, gcw, gcb, W1, b1, ws);
  hipLaunchKernelGGL(prepWg, dim3(200), dim3(128), 0, stream, esrc, edst, W1, ws);
  hipLaunchKernelGGL(pack, dim3(46), dim3(256), 0, stream, W1, W2, W3, ws);
  hipLaunchKernelGGL(fused_main, dim3(256), dim3(512), 0, stream,
                     x, apps, ws, b2, b3, W4, b4, out);
}